// Round 12
// baseline (783.430 us; speedup 1.0000x reference)
//
#include <hip/hip_runtime.h>
#include <math.h>

#define N_NODES 60
#define N_EDGES 1800
#define N_ETOT  1860
#define SLOPE   0.2f

// ---------------- LDS: small. conv c1+weights / gnn small arrays ----------------
#define CROW 18
#define CCH  (14 * CROW)         // 252
struct ConvS {
    float c1[6 * CCH];           // 1512 f
    float sw1[456], sb1[8];
    float sw2[2400], sb2[16];
};
struct GnnSmall {
    float as_[N_NODES], ad_[N_NODES], den_[N_NODES];
    float red[256];
    int cnt[N_NODES], off[N_NODES + 4];
};
union SMem { ConvS c; GnnSmall g; };     // 17.6 KB -> 7+ blocks/CU

__device__ __forceinline__ void block_reduce_sum(float v, float* red, float* out) {
    int tid = threadIdx.x;
    red[tid] = v;
    __syncthreads();
    for (int st = 128; st > 0; st >>= 1) {
        if (tid < st) red[tid] += red[tid + st];
        __syncthreads();
    }
    *out = red[0];
    __syncthreads();
}

// GNN: big arrays in global scratch (single block; L2-resident; latency hidden
// under the 8192 conv blocks). Small reductions in LDS.
__device__ void gat_layer(GnnSmall& S, const float* x_in, int in_dim, int out_dim,
                          const float* W, const float* a_src, const float* a_dst,
                          const float* We, const float* a_edge, const float* bias,
                          const float* edge_fea, float emean,
                          const int* gsrcs, const int* gdsts, const int* gcsr,
                          float* galpha, float* xl, float* outb) {
    const int tid = threadIdx.x, nt = blockDim.x;
    for (int idx = tid; idx < N_NODES * out_dim; idx += nt) {
        int i = idx / out_dim, j = idx % out_dim;
        float s = 0.f;
        for (int k = 0; k < in_dim; ++k) s += x_in[i * in_dim + k] * W[k * out_dim + j];
        xl[idx] = s;
    }
    __syncthreads();
    for (int i = tid; i < N_NODES; i += nt) {
        float s = 0.f, d = 0.f;
        for (int j = 0; j < out_dim; ++j) {
            s += xl[i * out_dim + j] * a_src[j];
            d += xl[i * out_dim + j] * a_dst[j];
        }
        S.as_[i] = s; S.ad_[i] = d;
    }
    float ecoef = 0.f;
    for (int j = 0; j < out_dim; ++j) ecoef += We[j] * a_edge[j];
    __syncthreads();
    for (int e = tid; e < N_ETOT; e += nt) {
        float eaval = (e < N_EDGES) ? edge_fea[e] : emean;
        float a = S.as_[gsrcs[e]] + S.ad_[gdsts[e]] + eaval * ecoef;
        galpha[e] = (a >= 0.f) ? a : SLOPE * a;
    }
    __syncthreads();
    for (int d = tid; d < N_NODES; d += nt) {
        float m = -INFINITY;
        for (int k = S.off[d]; k < S.off[d + 1]; ++k) m = fmaxf(m, galpha[gcsr[k]]);
        float den = 0.f;
        for (int k = S.off[d]; k < S.off[d + 1]; ++k) {
            int e = gcsr[k];
            float ex = expf(galpha[e] - m);
            galpha[e] = ex;
            den += ex;
        }
        S.den_[d] = den;
    }
    __syncthreads();
    for (int idx = tid; idx < N_NODES * out_dim; idx += nt) {
        int d = idx / out_dim, j = idx % out_dim;
        float s = 0.f;
        for (int k = S.off[d]; k < S.off[d + 1]; ++k) {
            int e = gcsr[k];
            s += galpha[e] * xl[gsrcs[e] * out_dim + j];
        }
        outb[idx] = s / S.den_[d] + bias[j];
    }
    __syncthreads();
}

__device__ void bn_relu(GnnSmall& S, float* v, int n) {   // in place
    const int tid = threadIdx.x, nt = blockDim.x;
    float s = 0.f;
    for (int i = tid; i < n; i += nt) s += v[i];
    float tot;
    block_reduce_sum(s, S.red, &tot);
    float avg = tot / n;
    float s2 = 0.f;
    for (int i = tid; i < n; i += nt) { float d = v[i] - avg; s2 += d * d; }
    block_reduce_sum(s2, S.red, &tot);
    float stdv = sqrtf(tot / n);
    __syncthreads();
    for (int i = tid; i < n; i += nt) v[i] = fmaxf((v[i] - avg) / stdv, 0.f);
    __syncthreads();
}

__device__ void gnn_path(GnnSmall& S,
    const float* node_fea, const float* edge_fea, const int* eidx,
    const float* g1w, const float* g1as, const float* g1ad,
    const float* g1we, const float* g1ae, const float* g1b,
    const float* g2w, const float* g2as, const float* g2ad,
    const float* g2we, const float* g2ae, const float* g2b,
    const float* fc1w, const float* fc1b, float* gcontrib,
    float* galpha, float* gx, float* gxl, int* gsrcs, int* gdsts, int* gcsr) {
    const int tid = threadIdx.x, nt = blockDim.x;
    float s = 0.f;
    for (int e = tid; e < N_EDGES; e += nt) s += edge_fea[e];
    float tot;
    block_reduce_sum(s, S.red, &tot);
    float emean = tot / N_EDGES;
    for (int e = tid; e < N_ETOT; e += nt) {
        if (e < N_EDGES) {
            gsrcs[e] = eidx[e];
            gdsts[e] = eidx[N_EDGES + e];
        } else {
            gsrcs[e] = e - N_EDGES;
            gdsts[e] = e - N_EDGES;
        }
    }
    if (tid < N_NODES) gx[tid] = node_fea[tid];
    __syncthreads();
    if (tid < N_NODES) {
        int c = 0;
        for (int e = 0; e < N_ETOT; ++e) c += (gdsts[e] == tid);
        S.cnt[tid] = c;
    }
    __syncthreads();
    if (tid == 0) {
        S.off[0] = 0;
        for (int d = 0; d < N_NODES; ++d) S.off[d + 1] = S.off[d] + S.cnt[d];
    }
    __syncthreads();
    if (tid < N_NODES) {
        int k = S.off[tid];
        for (int e = 0; e < N_ETOT; ++e)
            if (gdsts[e] == tid) gcsr[k++] = e;
    }
    __syncthreads();

    gat_layer(S, gx, 1, 6, g1w, g1as, g1ad, g1we, g1ae, g1b,
              edge_fea, emean, gsrcs, gdsts, gcsr, galpha, gxl, gx);
    bn_relu(S, gx, N_NODES * 6);
    gat_layer(S, gx, 6, 16, g2w, g2as, g2ad, g2we, g2ae, g2b,
              edge_fea, emean, gsrcs, gdsts, gcsr, galpha, gxl, gx);
    bn_relu(S, gx, N_NODES * 16);     // gx[0..959] == g

    for (int j = tid; j < 512; j += nt) {
        float acc = fc1b[j];
#pragma unroll 4
        for (int k = 0; k < 960; ++k) acc += gx[k] * fc1w[(size_t)k * 512 + j];
        gcontrib[j] = acc;
    }
}

// ---------------------------------------------------------------------------
// conv path: conv1 reads the image DIRECTLY FROM GLOBAL (12KB/block -> L1;
// lane order (py,qx,oc): same-window lanes coalesce/broadcast in TA; all
// float4 16B-aligned). Weights staged once in LDS (oc-stride 75=11 mod 32,
// 150=22 mod 32 -> distinct banks; same-oc lanes broadcast). c1 in small
// LDS (CROW=18: py-stride 36=4 mod 32 -> conflict-free b64). No simg LDS,
// one barrier. acc/wr/row compile-time indexed; unroll-1 on ic bounds live
// set (~55). relu(maxpool(x)) == maxpool(relu(x)).
// ---------------------------------------------------------------------------
__device__ void conv_path(ConvS& C, int img,
                          const float* __restrict__ pic,
                          const float* __restrict__ w1, const float* __restrict__ b1,
                          const float* __restrict__ w2, const float* __restrict__ b2,
                          float* __restrict__ p) {
    const int tid = threadIdx.x;

    for (int i = tid; i < 450; i += 256) C.sw1[i] = w1[i];
    if (tid < 6) C.sb1[tid] = b1[tid];
    for (int i = tid; i < 2400; i += 256) C.sw2[i] = w2[i];
    if (tid < 16) C.sb2[tid] = b2[tid];
    __syncthreads();

    const float* IMG = pic + (size_t)img * 3072;

    // ---- conv1: items (py,qx,oc) = 14*7*6 = 588; global reads, c1 to LDS ----
    for (int it = tid; it < 588; it += 256) {
        int py = it / 42, r = it % 42, qx = r / 6, oc = r % 6;
        int y0 = 2 * py, x0 = 4 * qx;
        float bias = C.sb1[oc];
        float acc[2][4];
#pragma unroll
        for (int dy = 0; dy < 2; ++dy)
#pragma unroll
            for (int dx = 0; dx < 4; ++dx) acc[dy][dx] = bias;

#pragma unroll 1
        for (int ic = 0; ic < 3; ++ic) {
            float wr[25];
#pragma unroll
            for (int k = 0; k < 25; ++k) wr[k] = C.sw1[oc * 75 + ic * 25 + k];
            const float* B = IMG + ic * 1024 + y0 * 32 + x0;
#pragma unroll
            for (int i = 0; i < 6; ++i) {
                float4 A = *(const float4*)(B + i * 32);
                float4 Bv = *(const float4*)(B + i * 32 + 4);
                float row[8] = {A.x, A.y, A.z, A.w, Bv.x, Bv.y, Bv.z, Bv.w};
#pragma unroll
                for (int dy = 0; dy < 2; ++dy) {
                    int ky = i - dy;
                    if (ky >= 0 && ky < 5) {
#pragma unroll
                        for (int dx = 0; dx < 4; ++dx) {
                            float s = 0.f;
#pragma unroll
                            for (int kx = 0; kx < 5; ++kx)
                                s += row[dx + kx] * wr[ky * 5 + kx];
                            acc[dy][dx] += s;
                        }
                    }
                }
            }
        }
#pragma unroll
        for (int sx = 0; sx < 2; ++sx) {
            float m = fmaxf(fmaxf(acc[0][2 * sx], acc[0][2 * sx + 1]),
                            fmaxf(acc[1][2 * sx], acc[1][2 * sx + 1]));
            C.c1[oc * CCH + py * CROW + 2 * qx + sx] = fmaxf(m, 0.f);
        }
    }
    __syncthreads();

    // ---- conv2: items (py,g,oc) = 5*3*16 = 240; c1 from LDS, p to global ----
    if (tid < 240) {
        int py = tid / 48, r = tid % 48, g = r / 16, oc = r % 16;
        int y0 = 2 * py, x0 = 4 * g;
        float bias = C.sb2[oc];
        float acc[2][4];
#pragma unroll
        for (int dy = 0; dy < 2; ++dy)
#pragma unroll
            for (int dx = 0; dx < 4; ++dx) acc[dy][dx] = bias;

#pragma unroll 1
        for (int ic = 0; ic < 6; ++ic) {
            float wr[25];
#pragma unroll
            for (int k = 0; k < 25; ++k) wr[k] = C.sw2[oc * 150 + ic * 25 + k];
            const float* B = &C.c1[ic * CCH + y0 * CROW + x0];
#pragma unroll
            for (int i = 0; i < 6; ++i) {
                const float2* rp = (const float2*)(B + i * CROW);   // CROW even
                float2 A = rp[0], Bv = rp[1], Cv = rp[2], Dv = rp[3];
                float row[8] = {A.x, A.y, Bv.x, Bv.y, Cv.x, Cv.y, Dv.x, Dv.y};
#pragma unroll
                for (int dy = 0; dy < 2; ++dy) {
                    int ky = i - dy;
                    if (ky >= 0 && ky < 5) {
#pragma unroll
                        for (int dx = 0; dx < 4; ++dx) {
                            float s = 0.f;
#pragma unroll
                            for (int kx = 0; kx < 5; ++kx)
                                s += row[dx + kx] * wr[ky * 5 + kx];
                            acc[dy][dx] += s;
                        }
                    }
                }
            }
        }
        float m0 = fmaxf(fmaxf(acc[0][0], acc[0][1]), fmaxf(acc[1][0], acc[1][1]));
        float m1 = fmaxf(fmaxf(acc[0][2], acc[0][3]), fmaxf(acc[1][2], acc[1][3]));
        float* prow = p + ((size_t)img * 16 + oc) * 25 + py * 5;
        prow[2 * g] = fmaxf(m0, 0.f);
        if (g < 2) prow[2 * g + 1] = fmaxf(m1, 0.f);
    }
}

// LDS 17.6KB -> 7 blocks/CU (28 waves); VGPR cap 512/7 = 73 (live ~55)
__global__ void __launch_bounds__(256, 7) fused_kernel(
    const float* __restrict__ node_fea, const float* __restrict__ edge_fea,
    const int* __restrict__ eidx,
    const float* g1w, const float* g1as, const float* g1ad,
    const float* g1we, const float* g1ae, const float* g1b,
    const float* g2w, const float* g2as, const float* g2ad,
    const float* g2we, const float* g2ae, const float* g2b,
    const float* __restrict__ fc1w, const float* __restrict__ fc1b,
    float* __restrict__ gcontrib,
    const float* __restrict__ pic,
    const float* __restrict__ c1w, const float* __restrict__ c1b,
    const float* __restrict__ c2w, const float* __restrict__ c2b,
    float* __restrict__ p,
    float* galpha, float* gx, float* gxl, int* gsrcs, int* gdsts, int* gcsr) {
    __shared__ SMem u;
    if (blockIdx.x == 0) {
        gnn_path(u.g, node_fea, edge_fea, eidx,
                 g1w, g1as, g1ad, g1we, g1ae, g1b,
                 g2w, g2as, g2ad, g2we, g2ae, g2b,
                 fc1w, fc1b, gcontrib, galpha, gx, gxl, gsrcs, gdsts, gcsr);
    } else {
        conv_path(u.c, blockIdx.x - 1, pic, c1w, c1b, c2w, c2b, p);
    }
}

// ---------------------------------------------------------------------------
// FC1: h[b,j] = relu(gcontrib[j] + sum_k p[b,k]*w2[k,j]); w2 = fc1_w[960:,:]
// ---------------------------------------------------------------------------
#define FC1_ROWS 16
__global__ void fc1_kernel(
    const float* __restrict__ p, const float* __restrict__ w,
    const float* __restrict__ gcontrib, float* __restrict__ h) {
    __shared__ float sp[FC1_ROWS * 400];
    const int tid = threadIdx.x;
    const size_t r0 = (size_t)blockIdx.x * FC1_ROWS;
    for (int i = tid; i < FC1_ROWS * 400; i += 256) sp[i] = p[r0 * 400 + i];
    __syncthreads();
    const int c0 = tid, c1 = tid + 256;
    float acc[FC1_ROWS][2];
#pragma unroll
    for (int r = 0; r < FC1_ROWS; ++r) { acc[r][0] = 0.f; acc[r][1] = 0.f; }
    for (int k = 0; k < 400; k += 4) {
        float wa0 = w[(size_t)(k + 0) * 512 + c0], wa1 = w[(size_t)(k + 0) * 512 + c1];
        float wb0 = w[(size_t)(k + 1) * 512 + c0], wb1 = w[(size_t)(k + 1) * 512 + c1];
        float wc0 = w[(size_t)(k + 2) * 512 + c0], wc1 = w[(size_t)(k + 2) * 512 + c1];
        float wd0 = w[(size_t)(k + 3) * 512 + c0], wd1 = w[(size_t)(k + 3) * 512 + c1];
#pragma unroll
        for (int r = 0; r < FC1_ROWS; ++r) {
            float4 pv = *(const float4*)&sp[r * 400 + k];
            acc[r][0] += pv.x * wa0 + pv.y * wb0 + pv.z * wc0 + pv.w * wd0;
            acc[r][1] += pv.x * wa1 + pv.y * wb1 + pv.z * wc1 + pv.w * wd1;
        }
    }
    float g0 = gcontrib[c0], g1 = gcontrib[c1];
#pragma unroll
    for (int r = 0; r < FC1_ROWS; ++r) {
        h[(r0 + r) * 512 + c0] = fmaxf(acc[r][0] + g0, 0.f);
        h[(r0 + r) * 512 + c1] = fmaxf(acc[r][1] + g1, 0.f);
    }
}

// ---------------------------------------------------------------------------
// FC2: out[b,j] = tanh(sum_k h[b,k]*fc2_w[k,j] + fc2_b[j]); one wave per row
// ---------------------------------------------------------------------------
__global__ void fc2_kernel(
    const float* __restrict__ h, const float* __restrict__ w,
    const float* __restrict__ b, float* __restrict__ out) {
    const int wave = threadIdx.x >> 6, lane = threadIdx.x & 63;
    const size_t row = (size_t)blockIdx.x * 4 + wave;
    const float* hr = h + row * 512;
    float partial[10];
#pragma unroll
    for (int j = 0; j < 10; ++j) partial[j] = 0.f;
    for (int k = lane; k < 512; k += 64) {
        float hv = hr[k];
        const float* wr = w + (size_t)k * 10;
#pragma unroll
        for (int j = 0; j < 10; ++j) partial[j] += hv * wr[j];
    }
#pragma unroll
    for (int j = 0; j < 10; ++j) {
        float v = partial[j];
        for (int sft = 32; sft > 0; sft >>= 1) v += __shfl_xor(v, sft, 64);
        partial[j] = v;
    }
    if (lane == 0) {
#pragma unroll
        for (int j = 0; j < 10; ++j)
            out[row * 10 + j] = tanhf(partial[j] + b[j]);
    }
}

extern "C" void kernel_launch(void* const* d_in, const int* in_sizes, int n_in,
                              void* d_out, int out_size, void* d_ws, size_t ws_size,
                              hipStream_t stream) {
    const float* node_fea = (const float*)d_in[0];
    const float* edge_fea = (const float*)d_in[1];
    const float* pic      = (const float*)d_in[2];
    const float* c1w = (const float*)d_in[3];
    const float* c1b = (const float*)d_in[4];
    const float* c2w = (const float*)d_in[5];
    const float* c2b = (const float*)d_in[6];
    const float* g1w  = (const float*)d_in[7];
    const float* g1as = (const float*)d_in[8];
    const float* g1ad = (const float*)d_in[9];
    const float* g1we = (const float*)d_in[10];
    const float* g1ae = (const float*)d_in[11];
    const float* g1b  = (const float*)d_in[12];
    const float* g2w  = (const float*)d_in[13];
    const float* g2as = (const float*)d_in[14];
    const float* g2ad = (const float*)d_in[15];
    const float* g2we = (const float*)d_in[16];
    const float* g2ae = (const float*)d_in[17];
    const float* g2b  = (const float*)d_in[18];
    const float* fc1w = (const float*)d_in[19];
    const float* fc1b = (const float*)d_in[20];
    const float* fc2w = (const float*)d_in[21];
    const float* fc2b = (const float*)d_in[22];
    const int*   eidx = (const int*)d_in[23];
    float* out = (float*)d_out;

    char* ws = (char*)d_ws;
    float* gcontrib = (float*)ws;                                     // 512 f
    float* p = (float*)(ws + 2048);                                   // 8192*400 f
    float* h = (float*)(ws + 2048 + (size_t)8192 * 400 * 4);          // 8192*512 f
    char*  gs = ws + 2048 + (size_t)8192 * 400 * 4 + (size_t)8192 * 512 * 4;
    float* galpha = (float*)gs;                    // 1860 f
    float* gx     = (float*)(gs + 7680);           // 960 f
    float* gxl    = (float*)(gs + 7680 + 3840);    // 960 f
    int*   gsrcs  = (int*)(gs + 15360);            // 1860 i
    int*   gdsts  = (int*)(gs + 15360 + 7680);     // 1860 i
    int*   gcsr   = (int*)(gs + 15360 + 15360);    // 1860 i

    hipLaunchKernelGGL(fused_kernel, dim3(8193), dim3(256), 0, stream,
                       node_fea, edge_fea, eidx,
                       g1w, g1as, g1ad, g1we, g1ae, g1b,
                       g2w, g2as, g2ad, g2we, g2ae, g2b,
                       fc1w, fc1b, gcontrib,
                       pic, c1w, c1b, c2w, c2b, p,
                       galpha, gx, gxl, gsrcs, gdsts, gcsr);
    hipLaunchKernelGGL(fc1_kernel, dim3(8192 / FC1_ROWS), dim3(256), 0, stream,
                       p, fc1w + (size_t)960 * 512, gcontrib, h);
    hipLaunchKernelGGL(fc2_kernel, dim3(8192 / 4), dim3(256), 0, stream,
                       h, fc2w, fc2b, out);
}

// Round 13
// 651.191 us; speedup vs baseline: 1.2031x; 1.2031x over previous
//
#include <hip/hip_runtime.h>
#include <math.h>

#define N_NODES 60
#define N_EDGES 1800
#define N_ETOT  1860
#define SLOPE   0.2f

// ---------------- LDS union ----------------
// conv: simg[3][32][32] unpadded (R8 layout: lane-consecutive reads, 3301
// conflicts measured) + c1[6][14][16]. GNN: small reductions only (big
// arrays live in global ws scratch, R12-verified).
#define CROW 16
#define CCH  (14 * CROW)         // 224
struct ConvS {
    float simg[3 * 32 * 32];     // 3072 f
    float c1[6 * CCH];           // 1344 f
    float pad[8];
};
struct GnnSmall {
    float as_[N_NODES], ad_[N_NODES], den_[N_NODES];
    float red[256];
    int cnt[N_NODES], off[N_NODES + 4];
};
union SMem { ConvS c; GnnSmall g; };     // ~17.7 KB

__device__ __forceinline__ void block_reduce_sum(float v, float* red, float* out) {
    int tid = threadIdx.x;
    red[tid] = v;
    __syncthreads();
    for (int st = 128; st > 0; st >>= 1) {
        if (tid < st) red[tid] += red[tid + st];
        __syncthreads();
    }
    *out = red[0];
    __syncthreads();
}

// GNN with big arrays in global scratch (verified in R12: same absmax)
__device__ void gat_layer(GnnSmall& S, const float* x_in, int in_dim, int out_dim,
                          const float* W, const float* a_src, const float* a_dst,
                          const float* We, const float* a_edge, const float* bias,
                          const float* edge_fea, float emean,
                          const int* gsrcs, const int* gdsts, const int* gcsr,
                          float* galpha, float* xl, float* outb) {
    const int tid = threadIdx.x, nt = blockDim.x;
    for (int idx = tid; idx < N_NODES * out_dim; idx += nt) {
        int i = idx / out_dim, j = idx % out_dim;
        float s = 0.f;
        for (int k = 0; k < in_dim; ++k) s += x_in[i * in_dim + k] * W[k * out_dim + j];
        xl[idx] = s;
    }
    __syncthreads();
    for (int i = tid; i < N_NODES; i += nt) {
        float s = 0.f, d = 0.f;
        for (int j = 0; j < out_dim; ++j) {
            s += xl[i * out_dim + j] * a_src[j];
            d += xl[i * out_dim + j] * a_dst[j];
        }
        S.as_[i] = s; S.ad_[i] = d;
    }
    float ecoef = 0.f;
    for (int j = 0; j < out_dim; ++j) ecoef += We[j] * a_edge[j];
    __syncthreads();
    for (int e = tid; e < N_ETOT; e += nt) {
        float eaval = (e < N_EDGES) ? edge_fea[e] : emean;
        float a = S.as_[gsrcs[e]] + S.ad_[gdsts[e]] + eaval * ecoef;
        galpha[e] = (a >= 0.f) ? a : SLOPE * a;
    }
    __syncthreads();
    for (int d = tid; d < N_NODES; d += nt) {
        float m = -INFINITY;
        for (int k = S.off[d]; k < S.off[d + 1]; ++k) m = fmaxf(m, galpha[gcsr[k]]);
        float den = 0.f;
        for (int k = S.off[d]; k < S.off[d + 1]; ++k) {
            int e = gcsr[k];
            float ex = expf(galpha[e] - m);
            galpha[e] = ex;
            den += ex;
        }
        S.den_[d] = den;
    }
    __syncthreads();
    for (int idx = tid; idx < N_NODES * out_dim; idx += nt) {
        int d = idx / out_dim, j = idx % out_dim;
        float s = 0.f;
        for (int k = S.off[d]; k < S.off[d + 1]; ++k) {
            int e = gcsr[k];
            s += galpha[e] * xl[gsrcs[e] * out_dim + j];
        }
        outb[idx] = s / S.den_[d] + bias[j];
    }
    __syncthreads();
}

__device__ void bn_relu(GnnSmall& S, float* v, int n) {   // in place
    const int tid = threadIdx.x, nt = blockDim.x;
    float s = 0.f;
    for (int i = tid; i < n; i += nt) s += v[i];
    float tot;
    block_reduce_sum(s, S.red, &tot);
    float avg = tot / n;
    float s2 = 0.f;
    for (int i = tid; i < n; i += nt) { float d = v[i] - avg; s2 += d * d; }
    block_reduce_sum(s2, S.red, &tot);
    float stdv = sqrtf(tot / n);
    __syncthreads();
    for (int i = tid; i < n; i += nt) v[i] = fmaxf((v[i] - avg) / stdv, 0.f);
    __syncthreads();
}

__device__ void gnn_path(GnnSmall& S,
    const float* node_fea, const float* edge_fea, const int* eidx,
    const float* g1w, const float* g1as, const float* g1ad,
    const float* g1we, const float* g1ae, const float* g1b,
    const float* g2w, const float* g2as, const float* g2ad,
    const float* g2we, const float* g2ae, const float* g2b,
    const float* fc1w, const float* fc1b, float* gcontrib,
    float* galpha, float* gx, float* gxl, int* gsrcs, int* gdsts, int* gcsr) {
    const int tid = threadIdx.x, nt = blockDim.x;
    float s = 0.f;
    for (int e = tid; e < N_EDGES; e += nt) s += edge_fea[e];
    float tot;
    block_reduce_sum(s, S.red, &tot);
    float emean = tot / N_EDGES;
    for (int e = tid; e < N_ETOT; e += nt) {
        if (e < N_EDGES) {
            gsrcs[e] = eidx[e];
            gdsts[e] = eidx[N_EDGES + e];
        } else {
            gsrcs[e] = e - N_EDGES;
            gdsts[e] = e - N_EDGES;
        }
    }
    if (tid < N_NODES) gx[tid] = node_fea[tid];
    __syncthreads();
    if (tid < N_NODES) {
        int c = 0;
        for (int e = 0; e < N_ETOT; ++e) c += (gdsts[e] == tid);
        S.cnt[tid] = c;
    }
    __syncthreads();
    if (tid == 0) {
        S.off[0] = 0;
        for (int d = 0; d < N_NODES; ++d) S.off[d + 1] = S.off[d] + S.cnt[d];
    }
    __syncthreads();
    if (tid < N_NODES) {
        int k = S.off[tid];
        for (int e = 0; e < N_ETOT; ++e)
            if (gdsts[e] == tid) gcsr[k++] = e;
    }
    __syncthreads();

    gat_layer(S, gx, 1, 6, g1w, g1as, g1ad, g1we, g1ae, g1b,
              edge_fea, emean, gsrcs, gdsts, gcsr, galpha, gxl, gx);
    bn_relu(S, gx, N_NODES * 6);
    gat_layer(S, gx, 6, 16, g2w, g2as, g2ad, g2we, g2ae, g2b,
              edge_fea, emean, gsrcs, gdsts, gcsr, galpha, gxl, gx);
    bn_relu(S, gx, N_NODES * 16);     // gx[0..959] == g

    for (int j = tid; j < 512; j += nt) {
        float acc = fc1b[j];
#pragma unroll 4
        for (int k = 0; k < 960; ++k) acc += gx[k] * fc1w[(size_t)k * 512 + j];
        gcontrib[j] = acc;
    }
}

// ---------------------------------------------------------------------------
// conv path: R8's verified inner loops (zero conflicts, zero spill at
// VGPR 64), restructured to 1 image / block with a 4-wave split -> half
// the LDS (17.7KB union) for 6 blocks/CU vs R8's 4 (the measured deficit
// was TLP: occupancy 20%, VALU 37%). Weights via wave-uniform global
// s_loads (K$), ic/ky unroll 1, acc compile-time indexed (rule #20).
// relu(maxpool(x)) == maxpool(relu(x)).
// ---------------------------------------------------------------------------
__device__ void conv_path(ConvS& C, int img,
                          const float* __restrict__ pic,
                          const float* __restrict__ w1, const float* __restrict__ b1,
                          const float* __restrict__ w2, const float* __restrict__ b2,
                          float* __restrict__ p) {
    const int tid = threadIdx.x;
    const int w = tid >> 6, lane = tid & 63;

    // stage 1 image (coalesced float4; LDS writes lane-consecutive)
    {
        const float4* src = (const float4*)(pic + (size_t)img * 3072);
        float4* dst = (float4*)C.simg;
        for (int i = tid; i < 768; i += 256) dst[i] = src[i];
    }
    __syncthreads();

    // ---- conv1: [3,32,32] -> pool -> c1[6,14,16] ----
    // wave w: half = w&1, jsel = w>>1; j = 4*jsel + jt (jt<4; j==7 masked)
    {
        const int half = w & 1, jsel = w >> 1;
        const int y_rel = lane >> 5, x = lane & 31;
        float acc[4][6];
#pragma unroll
        for (int jt = 0; jt < 4; ++jt)
#pragma unroll
            for (int oc = 0; oc < 6; ++oc) acc[jt][oc] = b1[oc];

#pragma unroll 1
        for (int ic = 0; ic < 3; ++ic)
#pragma unroll 1
            for (int ky = 0; ky < 5; ++ky) {
                float wv[6][5];
#pragma unroll
                for (int oc = 0; oc < 6; ++oc)
#pragma unroll
                    for (int kx = 0; kx < 5; ++kx)
                        wv[oc][kx] = w1[(oc * 3 + ic) * 25 + ky * 5 + kx];
                const float* Sc = C.simg + ic * 1024 + x;
#pragma unroll
                for (int jt = 0; jt < 4; ++jt) {
                    int j = 4 * jsel + jt;
                    int jc = (j < 7) ? j : 6;                    // j==7: garbage, masked
                    int row = 2 * (half + 2 * jc) + y_rel + ky;  // <= 31
                    const float* rp = Sc + row * 32;
                    float v0 = rp[0], v1 = rp[1], v2 = rp[2], v3 = rp[3], v4 = rp[4];
#pragma unroll
                    for (int oc = 0; oc < 6; ++oc)
                        acc[jt][oc] += v0 * wv[oc][0] + v1 * wv[oc][1] + v2 * wv[oc][2]
                                     + v3 * wv[oc][3] + v4 * wv[oc][4];
                }
            }
        // pool 2x2 (x-pair xor1, y-pair xor32) + relu, write c1
#pragma unroll
        for (int jt = 0; jt < 4; ++jt) {
            int j = 4 * jsel + jt;
            int yp = half + 2 * j;
#pragma unroll
            for (int oc = 0; oc < 6; ++oc) {
                float v = acc[jt][oc];
                v = fmaxf(v, __shfl_xor(v, 1, 64));
                v = fmaxf(v, __shfl_xor(v, 32, 64));
                v = fmaxf(v, 0.f);
                if (y_rel == 0 && (x & 1) == 0 && x < 28 && j < 7)
                    C.c1[oc * CCH + yp * CROW + (x >> 1)] = v;
            }
        }
    }
    __syncthreads();

    // ---- conv2: c1[6,14,16] -> pool -> p[16,5,5] ----
    // wave w owns oc = 4*w + o (o 0..3); 3 row-tasks (conv rows 4t..4t+3)
    {
        const int y_rel = lane >> 4, x = lane & 15;
        float acc[3][4];
#pragma unroll
        for (int t = 0; t < 3; ++t)
#pragma unroll
            for (int o = 0; o < 4; ++o) acc[t][o] = b2[4 * w + o];

#pragma unroll 1
        for (int ic = 0; ic < 6; ++ic)
#pragma unroll 1
            for (int ky = 0; ky < 5; ++ky) {
                float wv[4][5];
#pragma unroll
                for (int o = 0; o < 4; ++o)
#pragma unroll
                    for (int kx = 0; kx < 5; ++kx)
                        wv[o][kx] = w2[((4 * w + o) * 6 + ic) * 25 + ky * 5 + kx];
                const float* Cc = C.c1 + ic * CCH + x;
#pragma unroll
                for (int t = 0; t < 3; ++t) {
                    int row = 4 * t + y_rel + ky;
                    row = (row < 14) ? row : 13;                 // clamp garbage lanes
                    const float* rp = Cc + row * CROW;
                    float v0 = rp[0], v1 = rp[1], v2 = rp[2], v3 = rp[3], v4 = rp[4];
#pragma unroll
                    for (int o = 0; o < 4; ++o)
                        acc[t][o] += v0 * wv[o][0] + v1 * wv[o][1] + v2 * wv[o][2]
                                   + v3 * wv[o][3] + v4 * wv[o][4];
                }
            }
        // pool 2x2 (x-pair xor1, y-pair xor16) + relu, write p
#pragma unroll
        for (int t = 0; t < 3; ++t) {
#pragma unroll
            for (int o = 0; o < 4; ++o) {
                float v = acc[t][o];
                v = fmaxf(v, __shfl_xor(v, 1, 64));
                v = fmaxf(v, __shfl_xor(v, 16, 64));
                v = fmaxf(v, 0.f);
                int py = 2 * t + (y_rel >> 1);
                if ((y_rel & 1) == 0 && (x & 1) == 0 && x < 10 && py < 5) {
                    int oc = 4 * w + o;
                    p[((size_t)img * 16 + oc) * 25 + py * 5 + (x >> 1)] = v;
                }
            }
        }
    }
}

// LDS ~17.7KB -> 6 blocks/CU at (256,6); VGPR cap 85 (live ~60, headroom
// vs R12's forced-spill lesson)
__global__ void __launch_bounds__(256, 6) fused_kernel(
    const float* __restrict__ node_fea, const float* __restrict__ edge_fea,
    const int* __restrict__ eidx,
    const float* g1w, const float* g1as, const float* g1ad,
    const float* g1we, const float* g1ae, const float* g1b,
    const float* g2w, const float* g2as, const float* g2ad,
    const float* g2we, const float* g2ae, const float* g2b,
    const float* __restrict__ fc1w, const float* __restrict__ fc1b,
    float* __restrict__ gcontrib,
    const float* __restrict__ pic,
    const float* __restrict__ c1w, const float* __restrict__ c1b,
    const float* __restrict__ c2w, const float* __restrict__ c2b,
    float* __restrict__ p,
    float* galpha, float* gx, float* gxl, int* gsrcs, int* gdsts, int* gcsr) {
    __shared__ SMem u;
    if (blockIdx.x == 0) {
        gnn_path(u.g, node_fea, edge_fea, eidx,
                 g1w, g1as, g1ad, g1we, g1ae, g1b,
                 g2w, g2as, g2ad, g2we, g2ae, g2b,
                 fc1w, fc1b, gcontrib, galpha, gx, gxl, gsrcs, gdsts, gcsr);
    } else {
        conv_path(u.c, blockIdx.x - 1, pic, c1w, c1b, c2w, c2b, p);
    }
}

// ---------------------------------------------------------------------------
// FC1: h[b,j] = relu(gcontrib[j] + sum_k p[b,k]*w2[k,j]); w2 = fc1_w[960:,:]
// ---------------------------------------------------------------------------
#define FC1_ROWS 16
__global__ void fc1_kernel(
    const float* __restrict__ p, const float* __restrict__ w,
    const float* __restrict__ gcontrib, float* __restrict__ h) {
    __shared__ float sp[FC1_ROWS * 400];
    const int tid = threadIdx.x;
    const size_t r0 = (size_t)blockIdx.x * FC1_ROWS;
    for (int i = tid; i < FC1_ROWS * 400; i += 256) sp[i] = p[r0 * 400 + i];
    __syncthreads();
    const int c0 = tid, c1 = tid + 256;
    float acc[FC1_ROWS][2];
#pragma unroll
    for (int r = 0; r < FC1_ROWS; ++r) { acc[r][0] = 0.f; acc[r][1] = 0.f; }
    for (int k = 0; k < 400; k += 4) {
        float wa0 = w[(size_t)(k + 0) * 512 + c0], wa1 = w[(size_t)(k + 0) * 512 + c1];
        float wb0 = w[(size_t)(k + 1) * 512 + c0], wb1 = w[(size_t)(k + 1) * 512 + c1];
        float wc0 = w[(size_t)(k + 2) * 512 + c0], wc1 = w[(size_t)(k + 2) * 512 + c1];
        float wd0 = w[(size_t)(k + 3) * 512 + c0], wd1 = w[(size_t)(k + 3) * 512 + c1];
#pragma unroll
        for (int r = 0; r < FC1_ROWS; ++r) {
            float4 pv = *(const float4*)&sp[r * 400 + k];
            acc[r][0] += pv.x * wa0 + pv.y * wb0 + pv.z * wc0 + pv.w * wd0;
            acc[r][1] += pv.x * wa1 + pv.y * wb1 + pv.z * wc1 + pv.w * wd1;
        }
    }
    float g0 = gcontrib[c0], g1 = gcontrib[c1];
#pragma unroll
    for (int r = 0; r < FC1_ROWS; ++r) {
        h[(r0 + r) * 512 + c0] = fmaxf(acc[r][0] + g0, 0.f);
        h[(r0 + r) * 512 + c1] = fmaxf(acc[r][1] + g1, 0.f);
    }
}

// ---------------------------------------------------------------------------
// FC2: out[b,j] = tanh(sum_k h[b,k]*fc2_w[k,j] + fc2_b[j]); one wave per row
// ---------------------------------------------------------------------------
__global__ void fc2_kernel(
    const float* __restrict__ h, const float* __restrict__ w,
    const float* __restrict__ b, float* __restrict__ out) {
    const int wave = threadIdx.x >> 6, lane = threadIdx.x & 63;
    const size_t row = (size_t)blockIdx.x * 4 + wave;
    const float* hr = h + row * 512;
    float partial[10];
#pragma unroll
    for (int j = 0; j < 10; ++j) partial[j] = 0.f;
    for (int k = lane; k < 512; k += 64) {
        float hv = hr[k];
        const float* wr = w + (size_t)k * 10;
#pragma unroll
        for (int j = 0; j < 10; ++j) partial[j] += hv * wr[j];
    }
#pragma unroll
    for (int j = 0; j < 10; ++j) {
        float v = partial[j];
        for (int sft = 32; sft > 0; sft >>= 1) v += __shfl_xor(v, sft, 64);
        partial[j] = v;
    }
    if (lane == 0) {
#pragma unroll
        for (int j = 0; j < 10; ++j)
            out[row * 10 + j] = tanhf(partial[j] + b[j]);
    }
}

extern "C" void kernel_launch(void* const* d_in, const int* in_sizes, int n_in,
                              void* d_out, int out_size, void* d_ws, size_t ws_size,
                              hipStream_t stream) {
    const float* node_fea = (const float*)d_in[0];
    const float* edge_fea = (const float*)d_in[1];
    const float* pic      = (const float*)d_in[2];
    const float* c1w = (const float*)d_in[3];
    const float* c1b = (const float*)d_in[4];
    const float* c2w = (const float*)d_in[5];
    const float* c2b = (const float*)d_in[6];
    const float* g1w  = (const float*)d_in[7];
    const float* g1as = (const float*)d_in[8];
    const float* g1ad = (const float*)d_in[9];
    const float* g1we = (const float*)d_in[10];
    const float* g1ae = (const float*)d_in[11];
    const float* g1b  = (const float*)d_in[12];
    const float* g2w  = (const float*)d_in[13];
    const float* g2as = (const float*)d_in[14];
    const float* g2ad = (const float*)d_in[15];
    const float* g2we = (const float*)d_in[16];
    const float* g2ae = (const float*)d_in[17];
    const float* g2b  = (const float*)d_in[18];
    const float* fc1w = (const float*)d_in[19];
    const float* fc1b = (const float*)d_in[20];
    const float* fc2w = (const float*)d_in[21];
    const float* fc2b = (const float*)d_in[22];
    const int*   eidx = (const int*)d_in[23];
    float* out = (float*)d_out;

    char* ws = (char*)d_ws;
    float* gcontrib = (float*)ws;                                     // 512 f
    float* p = (float*)(ws + 2048);                                   // 8192*400 f
    float* h = (float*)(ws + 2048 + (size_t)8192 * 400 * 4);          // 8192*512 f
    char*  gs = ws + 2048 + (size_t)8192 * 400 * 4 + (size_t)8192 * 512 * 4;
    float* galpha = (float*)gs;                    // 1860 f
    float* gx     = (float*)(gs + 7680);           // 960 f
    float* gxl    = (float*)(gs + 7680 + 3840);    // 960 f
    int*   gsrcs  = (int*)(gs + 15360);            // 1860 i
    int*   gdsts  = (int*)(gs + 15360 + 7680);     // 1860 i
    int*   gcsr   = (int*)(gs + 15360 + 15360);    // 1860 i

    hipLaunchKernelGGL(fused_kernel, dim3(8193), dim3(256), 0, stream,
                       node_fea, edge_fea, eidx,
                       g1w, g1as, g1ad, g1we, g1ae, g1b,
                       g2w, g2as, g2ad, g2we, g2ae, g2b,
                       fc1w, fc1b, gcontrib,
                       pic, c1w, c1b, c2w, c2b, p,
                       galpha, gx, gxl, gsrcs, gdsts, gcsr);
    hipLaunchKernelGGL(fc1_kernel, dim3(8192 / FC1_ROWS), dim3(256), 0, stream,
                       p, fc1w + (size_t)960 * 512, gcontrib, h);
    hipLaunchKernelGGL(fc2_kernel, dim3(8192 / 4), dim3(256), 0, stream,
                       h, fc2w, fc2b, out);
}

// Round 14
// 601.848 us; speedup vs baseline: 1.3017x; 1.0820x over previous
//
#include <hip/hip_runtime.h>
#include <math.h>

#define N_NODES 60
#define N_EDGES 1800
#define N_ETOT  1860
#define SLOPE   0.2f

// ---------------- LDS union: conv path vs gnn path (block 0) ----------------
// simg stride 33 (odd): R1's only measured defect was stride-32 py-aliasing
// (delta-py=1 -> delta-addr 64 = 0 mod 32 banks -> ~5-way serialize, 7.1e7
// conflicts). Odd stride -> worst ~2-way = free (m136). c1 stride 15 likewise.
#define SROW 33
#define SCH  (32 * SROW)     // 1056
#define CROW 15
#define CCH  (14 * CROW)     // 210
struct ConvS {
    float simg[3 * SCH];     // 3168 f
    float sw1[452], sb1[8];
    float sw2[2400], sb2[16];
    float c1[6 * CCH];       // 1260 f
    float pad[8];
};                           // ~29.2 KB
struct GnnS {                // R9's slim layout (verified absmax 0.0039)
    float alpha[N_ETOT];
    float x_in[960];
    float xl[960];
    float as_[N_NODES], ad_[N_NODES], den_[N_NODES];
    float red[256];
    unsigned char srcs[N_ETOT], dsts[N_ETOT];
    unsigned short csr[N_ETOT];
    int cnt[N_NODES], off[N_NODES + 4];
};
union SMem { ConvS c; GnnS g; };

__device__ __forceinline__ void block_reduce_sum(float v, float* red, float* out) {
    int tid = threadIdx.x;
    red[tid] = v;
    __syncthreads();
    for (int st = 128; st > 0; st >>= 1) {
        if (tid < st) red[tid] += red[tid + st];
        __syncthreads();
    }
    *out = red[0];
    __syncthreads();
}

// outb may alias x_in: x_in only read in the xl loop, sync'd before writes
__device__ void gat_layer(GnnS& S, const float* x_in, int in_dim, int out_dim,
                          const float* W, const float* a_src, const float* a_dst,
                          const float* We, const float* a_edge, const float* bias,
                          const float* edge_fea, float emean,
                          float* xl, float* outb) {
    const int tid = threadIdx.x, nt = blockDim.x;
    for (int idx = tid; idx < N_NODES * out_dim; idx += nt) {
        int i = idx / out_dim, j = idx % out_dim;
        float s = 0.f;
        for (int k = 0; k < in_dim; ++k) s += x_in[i * in_dim + k] * W[k * out_dim + j];
        xl[idx] = s;
    }
    __syncthreads();
    for (int i = tid; i < N_NODES; i += nt) {
        float s = 0.f, d = 0.f;
        for (int j = 0; j < out_dim; ++j) {
            s += xl[i * out_dim + j] * a_src[j];
            d += xl[i * out_dim + j] * a_dst[j];
        }
        S.as_[i] = s; S.ad_[i] = d;
    }
    float ecoef = 0.f;
    for (int j = 0; j < out_dim; ++j) ecoef += We[j] * a_edge[j];
    __syncthreads();
    for (int e = tid; e < N_ETOT; e += nt) {
        float eaval = (e < N_EDGES) ? edge_fea[e] : emean;
        float a = S.as_[S.srcs[e]] + S.ad_[S.dsts[e]] + eaval * ecoef;
        S.alpha[e] = (a >= 0.f) ? a : SLOPE * a;
    }
    __syncthreads();
    for (int d = tid; d < N_NODES; d += nt) {
        float m = -INFINITY;
        for (int k = S.off[d]; k < S.off[d + 1]; ++k) m = fmaxf(m, S.alpha[S.csr[k]]);
        float den = 0.f;
        for (int k = S.off[d]; k < S.off[d + 1]; ++k) {
            int e = S.csr[k];
            float ex = expf(S.alpha[e] - m);
            S.alpha[e] = ex;
            den += ex;
        }
        S.den_[d] = den;
    }
    __syncthreads();
    for (int idx = tid; idx < N_NODES * out_dim; idx += nt) {
        int d = idx / out_dim, j = idx % out_dim;
        float s = 0.f;
        for (int k = S.off[d]; k < S.off[d + 1]; ++k) {
            int e = S.csr[k];
            s += S.alpha[e] * xl[(int)S.srcs[e] * out_dim + j];
        }
        outb[idx] = s / S.den_[d] + bias[j];
    }
    __syncthreads();
}

__device__ void bn_relu(GnnS& S, float* v, int n) {   // in place
    const int tid = threadIdx.x, nt = blockDim.x;
    float s = 0.f;
    for (int i = tid; i < n; i += nt) s += v[i];
    float tot;
    block_reduce_sum(s, S.red, &tot);
    float avg = tot / n;
    float s2 = 0.f;
    for (int i = tid; i < n; i += nt) { float d = v[i] - avg; s2 += d * d; }
    block_reduce_sum(s2, S.red, &tot);
    float stdv = sqrtf(tot / n);
    __syncthreads();
    for (int i = tid; i < n; i += nt) v[i] = fmaxf((v[i] - avg) / stdv, 0.f);
    __syncthreads();
}

__device__ void gnn_path(GnnS& S,
    const float* node_fea, const float* edge_fea, const int* eidx,
    const float* g1w, const float* g1as, const float* g1ad,
    const float* g1we, const float* g1ae, const float* g1b,
    const float* g2w, const float* g2as, const float* g2ad,
    const float* g2we, const float* g2ae, const float* g2b,
    const float* fc1w, const float* fc1b, float* gcontrib) {
    const int tid = threadIdx.x, nt = blockDim.x;
    float s = 0.f;
    for (int e = tid; e < N_EDGES; e += nt) s += edge_fea[e];
    float tot;
    block_reduce_sum(s, S.red, &tot);
    float emean = tot / N_EDGES;
    for (int e = tid; e < N_ETOT; e += nt) {
        if (e < N_EDGES) {
            S.srcs[e] = (unsigned char)eidx[e];
            S.dsts[e] = (unsigned char)eidx[N_EDGES + e];
        } else {
            S.srcs[e] = (unsigned char)(e - N_EDGES);
            S.dsts[e] = (unsigned char)(e - N_EDGES);
        }
    }
    if (tid < N_NODES) S.x_in[tid] = node_fea[tid];
    __syncthreads();
    if (tid < N_NODES) {
        int c = 0;
        for (int e = 0; e < N_ETOT; ++e) c += (S.dsts[e] == tid);
        S.cnt[tid] = c;
    }
    __syncthreads();
    if (tid == 0) {
        S.off[0] = 0;
        for (int d = 0; d < N_NODES; ++d) S.off[d + 1] = S.off[d] + S.cnt[d];
    }
    __syncthreads();
    if (tid < N_NODES) {
        int k = S.off[tid];
        for (int e = 0; e < N_ETOT; ++e)
            if (S.dsts[e] == tid) S.csr[k++] = (unsigned short)e;
    }
    __syncthreads();

    gat_layer(S, S.x_in, 1, 6, g1w, g1as, g1ad, g1we, g1ae, g1b,
              edge_fea, emean, S.xl, S.x_in);
    bn_relu(S, S.x_in, N_NODES * 6);
    gat_layer(S, S.x_in, 6, 16, g2w, g2as, g2ad, g2we, g2ae, g2b,
              edge_fea, emean, S.xl, S.x_in);
    bn_relu(S, S.x_in, N_NODES * 16);   // x_in[0..959] == g

    for (int j = tid; j < 512; j += nt) {
        float acc = fc1b[j];
#pragma unroll 4
        for (int k = 0; k < 960; ++k) acc += S.x_in[k] * fc1w[(size_t)k * 512 + j];
        gcontrib[j] = acc;
    }
}

// ---------------------------------------------------------------------------
// conv path: EXACTLY R1's thread-per-output structure (best measured: 350us,
// VALU 53%, VGPR 56, no spill, max ILP from full unrolls + no serial weight
// loads + no mid-loop barriers) with the ONLY measured defect fixed: odd LDS
// strides kill the stride-32 py-alias bank conflicts (7.1e7 -> ~free).
// relu(maxpool(x)) == maxpool(relu(x)).
// ---------------------------------------------------------------------------
__device__ void conv_path(ConvS& C, int img,
                          const float* __restrict__ pic,
                          const float* __restrict__ w1, const float* __restrict__ b1,
                          const float* __restrict__ w2, const float* __restrict__ b2,
                          float* __restrict__ p) {
    const int tid = threadIdx.x;
    const float* img_p = pic + (size_t)img * 3072;
    for (int i = tid; i < 3072; i += 256) {
        int ic = i >> 10, rem = i & 1023, y = rem >> 5, x = rem & 31;
        C.simg[ic * SCH + y * SROW + x] = img_p[i];
    }
    for (int i = tid; i < 450; i += 256) C.sw1[i] = w1[i];
    if (tid < 6) C.sb1[tid] = b1[tid];
    for (int i = tid; i < 2400; i += 256) C.sw2[i] = w2[i];
    if (tid < 16) C.sb2[tid] = b2[tid];
    __syncthreads();

    // conv1 [3,32,32] -> relu/pool -> c1[6,14,.]
    for (int o = tid; o < 6 * 14 * 14; o += 256) {
        int oc = o / 196, r = o % 196, py = r / 14, px = r % 14;
        float mx = -INFINITY;
        for (int dy = 0; dy < 2; ++dy)
            for (int dx = 0; dx < 2; ++dx) {
                int y0 = 2 * py + dy, x0 = 2 * px + dx;
                float acc = C.sb1[oc];
                for (int ic = 0; ic < 3; ++ic) {
                    const float* ip = &C.simg[ic * SCH + y0 * SROW + x0];
                    const float* wp = &C.sw1[oc * 75 + ic * 25];
#pragma unroll
                    for (int ky = 0; ky < 5; ++ky)
#pragma unroll
                        for (int kx = 0; kx < 5; ++kx)
                            acc += ip[ky * SROW + kx] * wp[ky * 5 + kx];
                }
                mx = fmaxf(mx, acc);
            }
        C.c1[oc * CCH + py * CROW + px] = fmaxf(mx, 0.f);
    }
    __syncthreads();

    // conv2 c1[6,14,.] -> relu/pool -> p[16,5,5]
    for (int o = tid; o < 400; o += 256) {
        int oc = o / 25, r = o % 25, py = r / 5, px = r % 5;
        float mx = -INFINITY;
        for (int dy = 0; dy < 2; ++dy)
            for (int dx = 0; dx < 2; ++dx) {
                int y0 = 2 * py + dy, x0 = 2 * px + dx;
                float acc = C.sb2[oc];
                for (int ic = 0; ic < 6; ++ic) {
                    const float* ip = &C.c1[ic * CCH + y0 * CROW + x0];
                    const float* wp = &C.sw2[oc * 150 + ic * 25];
#pragma unroll
                    for (int ky = 0; ky < 5; ++ky)
#pragma unroll
                        for (int kx = 0; kx < 5; ++kx)
                            acc += ip[ky * CROW + kx] * wp[ky * 5 + kx];
                }
                mx = fmaxf(mx, acc);
            }
        p[(size_t)img * 400 + o] = fmaxf(mx, 0.f);
    }
}

// Plain (256) like R1: let the allocator pick (R1 chose VGPR 56, no spill).
// LDS union 29.2KB -> 5 blocks/CU.
__global__ void __launch_bounds__(256) fused_kernel(
    const float* __restrict__ node_fea, const float* __restrict__ edge_fea,
    const int* __restrict__ eidx,
    const float* g1w, const float* g1as, const float* g1ad,
    const float* g1we, const float* g1ae, const float* g1b,
    const float* g2w, const float* g2as, const float* g2ad,
    const float* g2we, const float* g2ae, const float* g2b,
    const float* __restrict__ fc1w, const float* __restrict__ fc1b,
    float* __restrict__ gcontrib,
    const float* __restrict__ pic,
    const float* __restrict__ c1w, const float* __restrict__ c1b,
    const float* __restrict__ c2w, const float* __restrict__ c2b,
    float* __restrict__ p) {
    __shared__ SMem u;
    if (blockIdx.x == 0) {
        gnn_path(u.g, node_fea, edge_fea, eidx,
                 g1w, g1as, g1ad, g1we, g1ae, g1b,
                 g2w, g2as, g2ad, g2we, g2ae, g2b,
                 fc1w, fc1b, gcontrib);
    } else {
        conv_path(u.c, blockIdx.x - 1, pic, c1w, c1b, c2w, c2b, p);
    }
}

// ---------------------------------------------------------------------------
// FC1: h[b,j] = relu(gcontrib[j] + sum_k p[b,k]*w2[k,j]); w2 = fc1_w[960:,:]
// ---------------------------------------------------------------------------
#define FC1_ROWS 16
__global__ void fc1_kernel(
    const float* __restrict__ p, const float* __restrict__ w,
    const float* __restrict__ gcontrib, float* __restrict__ h) {
    __shared__ float sp[FC1_ROWS * 400];
    const int tid = threadIdx.x;
    const size_t r0 = (size_t)blockIdx.x * FC1_ROWS;
    for (int i = tid; i < FC1_ROWS * 400; i += 256) sp[i] = p[r0 * 400 + i];
    __syncthreads();
    const int c0 = tid, c1 = tid + 256;
    float acc[FC1_ROWS][2];
#pragma unroll
    for (int r = 0; r < FC1_ROWS; ++r) { acc[r][0] = 0.f; acc[r][1] = 0.f; }
    for (int k = 0; k < 400; k += 4) {
        float wa0 = w[(size_t)(k + 0) * 512 + c0], wa1 = w[(size_t)(k + 0) * 512 + c1];
        float wb0 = w[(size_t)(k + 1) * 512 + c0], wb1 = w[(size_t)(k + 1) * 512 + c1];
        float wc0 = w[(size_t)(k + 2) * 512 + c0], wc1 = w[(size_t)(k + 2) * 512 + c1];
        float wd0 = w[(size_t)(k + 3) * 512 + c0], wd1 = w[(size_t)(k + 3) * 512 + c1];
#pragma unroll
        for (int r = 0; r < FC1_ROWS; ++r) {
            float4 pv = *(const float4*)&sp[r * 400 + k];
            acc[r][0] += pv.x * wa0 + pv.y * wb0 + pv.z * wc0 + pv.w * wd0;
            acc[r][1] += pv.x * wa1 + pv.y * wb1 + pv.z * wc1 + pv.w * wd1;
        }
    }
    float g0 = gcontrib[c0], g1 = gcontrib[c1];
#pragma unroll
    for (int r = 0; r < FC1_ROWS; ++r) {
        h[(r0 + r) * 512 + c0] = fmaxf(acc[r][0] + g0, 0.f);
        h[(r0 + r) * 512 + c1] = fmaxf(acc[r][1] + g1, 0.f);
    }
}

// ---------------------------------------------------------------------------
// FC2: out[b,j] = tanh(sum_k h[b,k]*fc2_w[k,j] + fc2_b[j]); one wave per row
// ---------------------------------------------------------------------------
__global__ void fc2_kernel(
    const float* __restrict__ h, const float* __restrict__ w,
    const float* __restrict__ b, float* __restrict__ out) {
    const int wave = threadIdx.x >> 6, lane = threadIdx.x & 63;
    const size_t row = (size_t)blockIdx.x * 4 + wave;
    const float* hr = h + row * 512;
    float partial[10];
#pragma unroll
    for (int j = 0; j < 10; ++j) partial[j] = 0.f;
    for (int k = lane; k < 512; k += 64) {
        float hv = hr[k];
        const float* wr = w + (size_t)k * 10;
#pragma unroll
        for (int j = 0; j < 10; ++j) partial[j] += hv * wr[j];
    }
#pragma unroll
    for (int j = 0; j < 10; ++j) {
        float v = partial[j];
        for (int sft = 32; sft > 0; sft >>= 1) v += __shfl_xor(v, sft, 64);
        partial[j] = v;
    }
    if (lane == 0) {
#pragma unroll
        for (int j = 0; j < 10; ++j)
            out[row * 10 + j] = tanhf(partial[j] + b[j]);
    }
}

extern "C" void kernel_launch(void* const* d_in, const int* in_sizes, int n_in,
                              void* d_out, int out_size, void* d_ws, size_t ws_size,
                              hipStream_t stream) {
    const float* node_fea = (const float*)d_in[0];
    const float* edge_fea = (const float*)d_in[1];
    const float* pic      = (const float*)d_in[2];
    const float* c1w = (const float*)d_in[3];
    const float* c1b = (const float*)d_in[4];
    const float* c2w = (const float*)d_in[5];
    const float* c2b = (const float*)d_in[6];
    const float* g1w  = (const float*)d_in[7];
    const float* g1as = (const float*)d_in[8];
    const float* g1ad = (const float*)d_in[9];
    const float* g1we = (const float*)d_in[10];
    const float* g1ae = (const float*)d_in[11];
    const float* g1b  = (const float*)d_in[12];
    const float* g2w  = (const float*)d_in[13];
    const float* g2as = (const float*)d_in[14];
    const float* g2ad = (const float*)d_in[15];
    const float* g2we = (const float*)d_in[16];
    const float* g2ae = (const float*)d_in[17];
    const float* g2b  = (const float*)d_in[18];
    const float* fc1w = (const float*)d_in[19];
    const float* fc1b = (const float*)d_in[20];
    const float* fc2w = (const float*)d_in[21];
    const float* fc2b = (const float*)d_in[22];
    const int*   eidx = (const int*)d_in[23];
    float* out = (float*)d_out;

    char* ws = (char*)d_ws;
    float* gcontrib = (float*)ws;                                   // 512 f
    float* p = (float*)(ws + 2048);                                 // 8192*400 f
    float* h = (float*)(ws + 2048 + (size_t)8192 * 400 * 4);        // 8192*512 f

    hipLaunchKernelGGL(fused_kernel, dim3(8193), dim3(256), 0, stream,
                       node_fea, edge_fea, eidx,
                       g1w, g1as, g1ad, g1we, g1ae, g1b,
                       g2w, g2as, g2ad, g2we, g2ae, g2b,
                       fc1w, fc1b, gcontrib,
                       pic, c1w, c1b, c2w, c2b, p);
    hipLaunchKernelGGL(fc1_kernel, dim3(8192 / FC1_ROWS), dim3(256), 0, stream,
                       p, fc1w + (size_t)960 * 512, gcontrib, h);
    hipLaunchKernelGGL(fc2_kernel, dim3(8192 / 4), dim3(256), 0, stream,
                       h, fc2w, fc2b, out);
}

// Round 16
// 435.120 us; speedup vs baseline: 1.8005x; 1.3832x over previous
//
#include <hip/hip_runtime.h>
#include <math.h>

#define N_NODES 60
#define N_EDGES 1800
#define N_ETOT  1860
#define SLOPE   0.2f

// ---------------- LDS union: conv path vs gnn path (block 0) ----------------
// conv: R8's exact layout + weights staged in LDS (the one change vs R8: hot
// loop becomes DS-only; R8's per-(ic,ky) global s_loads shared lgkmcnt with
// ds_read and forced full drains -> 37% VALU).
struct ConvS {
    float simg[2 * 3 * 32 * 32];   // 6144 f
    float c1[2 * 6 * 14 * 16];     // 2688 f
    float sw1[452], sb1[8];
    float sw2[2400], sb2[16];
    float pad[16];
};                                  // ~46.6 KB -> 3 blocks/CU
struct GnnS {
    float ea[N_ETOT];
    float alpha[N_ETOT];
    float x_in[960];
    float xl[960];
    float as_[N_NODES], ad_[N_NODES], den_[N_NODES];
    float red[256];
    unsigned char srcs[N_ETOT], dsts[N_ETOT];
    unsigned short csr[N_ETOT];
    int cnt[N_NODES], off[N_NODES + 4];
};
union SMem { ConvS c; GnnS g; };

__device__ __forceinline__ void block_reduce_sum(float v, float* red, float* out) {
    int tid = threadIdx.x;
    red[tid] = v;
    __syncthreads();
    for (int st = 128; st > 0; st >>= 1) {
        if (tid < st) red[tid] += red[tid + st];
        __syncthreads();
    }
    *out = red[0];
    __syncthreads();
}

// outb may alias x_in: x_in is only read in the first (xl) loop, which is
// barrier-separated from the final write loop (R9/R11-verified flow).
__device__ void gat_layer(GnnS& S, const float* x_in, int in_dim, int out_dim,
                          const float* W, const float* a_src, const float* a_dst,
                          const float* We, const float* a_edge, const float* bias,
                          float* xl, float* outb) {
    const int tid = threadIdx.x, nt = blockDim.x;
    for (int idx = tid; idx < N_NODES * out_dim; idx += nt) {
        int i = idx / out_dim, j = idx % out_dim;
        float s = 0.f;
        for (int k = 0; k < in_dim; ++k) s += x_in[i * in_dim + k] * W[k * out_dim + j];
        xl[idx] = s;
    }
    __syncthreads();
    for (int i = tid; i < N_NODES; i += nt) {
        float s = 0.f, d = 0.f;
        for (int j = 0; j < out_dim; ++j) {
            s += xl[i * out_dim + j] * a_src[j];
            d += xl[i * out_dim + j] * a_dst[j];
        }
        S.as_[i] = s; S.ad_[i] = d;
    }
    float ecoef = 0.f;
    for (int j = 0; j < out_dim; ++j) ecoef += We[j] * a_edge[j];
    __syncthreads();
    for (int e = tid; e < N_ETOT; e += nt) {
        float a = S.as_[S.srcs[e]] + S.ad_[S.dsts[e]] + S.ea[e] * ecoef;
        S.alpha[e] = (a >= 0.f) ? a : SLOPE * a;
    }
    __syncthreads();
    for (int d = tid; d < N_NODES; d += nt) {
        float m = -INFINITY;
        for (int k = S.off[d]; k < S.off[d + 1]; ++k) m = fmaxf(m, S.alpha[S.csr[k]]);
        float den = 0.f;
        for (int k = S.off[d]; k < S.off[d + 1]; ++k) {
            int e = S.csr[k];
            float ex = expf(S.alpha[e] - m);
            S.alpha[e] = ex;
            den += ex;
        }
        S.den_[d] = den;
    }
    __syncthreads();
    for (int idx = tid; idx < N_NODES * out_dim; idx += nt) {
        int d = idx / out_dim, j = idx % out_dim;
        float s = 0.f;
        for (int k = S.off[d]; k < S.off[d + 1]; ++k) {
            int e = S.csr[k];
            s += S.alpha[e] * xl[(int)S.srcs[e] * out_dim + j];
        }
        outb[idx] = s / S.den_[d] + bias[j];
    }
    __syncthreads();
}

__device__ void bn_relu(GnnS& S, float* v, int n) {   // in place
    const int tid = threadIdx.x, nt = blockDim.x;
    float s = 0.f;
    for (int i = tid; i < n; i += nt) s += v[i];
    float tot;
    block_reduce_sum(s, S.red, &tot);
    float avg = tot / n;
    float s2 = 0.f;
    for (int i = tid; i < n; i += nt) { float d = v[i] - avg; s2 += d * d; }
    block_reduce_sum(s2, S.red, &tot);
    float stdv = sqrtf(tot / n);
    __syncthreads();
    for (int i = tid; i < n; i += nt) v[i] = fmaxf((v[i] - avg) / stdv, 0.f);
    __syncthreads();
}

__device__ void gnn_run(GnnS& S,
    const float* node_fea, const float* edge_fea, const int* eidx,
    const float* g1w, const float* g1as, const float* g1ad,
    const float* g1we, const float* g1ae, const float* g1b,
    const float* g2w, const float* g2as, const float* g2ad,
    const float* g2we, const float* g2ae, const float* g2b,
    const float* fc1w, const float* fc1b, float* gcontrib) {
    const int tid = threadIdx.x, nt = blockDim.x;
    float s = 0.f;
    for (int e = tid; e < N_EDGES; e += nt) s += edge_fea[e];
    float tot;
    block_reduce_sum(s, S.red, &tot);
    float emean = tot / N_EDGES;
    for (int e = tid; e < N_ETOT; e += nt) {
        if (e < N_EDGES) {
            S.ea[e] = edge_fea[e];
            S.srcs[e] = (unsigned char)eidx[e];
            S.dsts[e] = (unsigned char)eidx[N_EDGES + e];
        } else {
            S.ea[e] = emean;
            S.srcs[e] = (unsigned char)(e - N_EDGES);
            S.dsts[e] = (unsigned char)(e - N_EDGES);
        }
    }
    if (tid < N_NODES) S.x_in[tid] = node_fea[tid];
    __syncthreads();
    if (tid < N_NODES) {
        int c = 0;
        for (int e = 0; e < N_ETOT; ++e) c += (S.dsts[e] == tid);
        S.cnt[tid] = c;
    }
    __syncthreads();
    if (tid == 0) {
        S.off[0] = 0;
        for (int d = 0; d < N_NODES; ++d) S.off[d + 1] = S.off[d] + S.cnt[d];
    }
    __syncthreads();
    if (tid < N_NODES) {
        int k = S.off[tid];
        for (int e = 0; e < N_ETOT; ++e)
            if (S.dsts[e] == tid) S.csr[k++] = (unsigned short)e;
    }
    __syncthreads();

    gat_layer(S, S.x_in, 1, 6, g1w, g1as, g1ad, g1we, g1ae, g1b, S.xl, S.x_in);
    bn_relu(S, S.x_in, N_NODES * 6);
    gat_layer(S, S.x_in, 6, 16, g2w, g2as, g2ad, g2we, g2ae, g2b, S.xl, S.x_in);
    bn_relu(S, S.x_in, N_NODES * 16);   // x_in[0..959] == g

    for (int j = tid; j < 512; j += nt) {
        float acc = fc1b[j];
#pragma unroll 4
        for (int k = 0; k < 960; ++k) acc += S.x_in[k] * fc1w[(size_t)k * 512 + j];
        gcontrib[j] = acc;
    }
}

// ---------------------------------------------------------------------------
// conv path: R8 verbatim (zero conflicts, zero spill, best total 426.9us)
// except weights/bias read from LDS (broadcast ds_read, uniform addr =
// conflict-free) instead of per-(ic,ky) global s_loads -> hot loop DS-only,
// fine-grained lgkmcnt(N) overlap instead of full drains.
// relu(maxpool(x)) == maxpool(relu(x)).
// ---------------------------------------------------------------------------
__device__ void conv_path(ConvS& C, int img0,
                          const float* __restrict__ pic,
                          const float* __restrict__ w1, const float* __restrict__ b1,
                          const float* __restrict__ w2, const float* __restrict__ b2,
                          float* __restrict__ p) {
    const int tid = threadIdx.x;
    const int w = tid >> 6, lane = tid & 63;

    // stage 2 images + all weights (one-time; hot loops are then DS-only)
    {
        const float4* src = (const float4*)(pic + (size_t)img0 * 3072);
        float4* dst = (float4*)C.simg;
        for (int i = tid; i < 1536; i += 256) dst[i] = src[i];
        for (int i = tid; i < 450; i += 256) C.sw1[i] = w1[i];
        if (tid < 6) C.sb1[tid] = b1[tid];
        for (int i = tid; i < 2400; i += 256) C.sw2[i] = w2[i];
        if (tid < 16) C.sb2[tid] = b2[tid];
    }
    __syncthreads();

    // ---------------- conv1: [3,32,32] -> pool -> c1[6,14,16] ----------------
    // wave w: img = w>>1, ypairs {half, half+2, ..., half+12}, half = w&1
    {
        const int img = w >> 1, half = w & 1;
        const int y_rel = lane >> 5, x = lane & 31;
        const float* S = C.simg + img * 3072;
        float acc[7][6];
#pragma unroll
        for (int j = 0; j < 7; ++j)
#pragma unroll
            for (int oc = 0; oc < 6; ++oc) acc[j][oc] = C.sb1[oc];

#pragma unroll 1
        for (int ic = 0; ic < 3; ++ic)
#pragma unroll 1
            for (int ky = 0; ky < 5; ++ky) {
                float wv[6][5];
#pragma unroll
                for (int oc = 0; oc < 6; ++oc)
#pragma unroll
                    for (int kx = 0; kx < 5; ++kx)
                        wv[oc][kx] = C.sw1[(oc * 3 + ic) * 25 + ky * 5 + kx];
                const float* Sc = S + ic * 1024 + x;
#pragma unroll
                for (int j = 0; j < 7; ++j) {
                    int row = 2 * (half + 2 * j) + y_rel + ky;   // <= 31
                    const float* rp = Sc + row * 32;
                    float v0 = rp[0], v1 = rp[1], v2 = rp[2], v3 = rp[3], v4 = rp[4];
#pragma unroll
                    for (int oc = 0; oc < 6; ++oc)
                        acc[j][oc] += v0 * wv[oc][0] + v1 * wv[oc][1] + v2 * wv[oc][2]
                                    + v3 * wv[oc][3] + v4 * wv[oc][4];
                }
            }
        // pool 2x2 (x-pair xor1, y-pair xor32) + relu, write c1
#pragma unroll
        for (int j = 0; j < 7; ++j) {
            int yp = half + 2 * j;
#pragma unroll
            for (int oc = 0; oc < 6; ++oc) {
                float v = acc[j][oc];
                v = fmaxf(v, __shfl_xor(v, 1, 64));
                v = fmaxf(v, __shfl_xor(v, 32, 64));
                v = fmaxf(v, 0.f);
                if (y_rel == 0 && (x & 1) == 0 && x < 28)
                    C.c1[((img * 6 + oc) * 14 + yp) * 16 + (x >> 1)] = v;
            }
        }
    }
    __syncthreads();

    // ---------------- conv2: c1[6,14,16] -> pool -> p[16,5,5] ----------------
    // wave w: img = w>>1, oc-half = w&1; 3 row-tasks (conv rows 4t..4t+3)
    {
        const int img = w >> 1, och = w & 1;
        const int y_rel = lane >> 4, x = lane & 15;
        const float* C1 = C.c1 + img * (6 * 14 * 16);
        float acc[3][8];
#pragma unroll
        for (int t = 0; t < 3; ++t)
#pragma unroll
            for (int o = 0; o < 8; ++o) acc[t][o] = C.sb2[och * 8 + o];

#pragma unroll 1
        for (int ic = 0; ic < 6; ++ic)
#pragma unroll 1
            for (int ky = 0; ky < 5; ++ky) {
                float wv[8][5];
#pragma unroll
                for (int o = 0; o < 8; ++o)
#pragma unroll
                    for (int kx = 0; kx < 5; ++kx)
                        wv[o][kx] = C.sw2[((och * 8 + o) * 6 + ic) * 25 + ky * 5 + kx];
                const float* Cc = C1 + ic * 224 + x;
#pragma unroll
                for (int t = 0; t < 3; ++t) {
                    int row = 4 * t + y_rel + ky;
                    row = (row < 14) ? row : 13;                 // clamp garbage lanes
                    const float* rp = Cc + row * 16;
                    float v0 = rp[0], v1 = rp[1], v2 = rp[2], v3 = rp[3], v4 = rp[4];
#pragma unroll
                    for (int o = 0; o < 8; ++o)
                        acc[t][o] += v0 * wv[o][0] + v1 * wv[o][1] + v2 * wv[o][2]
                                   + v3 * wv[o][3] + v4 * wv[o][4];
                }
            }
        // pool 2x2 (x-pair xor1, y-pair xor16) + relu, write p
#pragma unroll
        for (int t = 0; t < 3; ++t) {
#pragma unroll
            for (int o = 0; o < 8; ++o) {
                float v = acc[t][o];
                v = fmaxf(v, __shfl_xor(v, 1, 64));
                v = fmaxf(v, __shfl_xor(v, 16, 64));
                v = fmaxf(v, 0.f);
                int py = 2 * t + (y_rel >> 1);
                if ((y_rel & 1) == 0 && (x & 1) == 0 && x < 10 && py < 5) {
                    int oc = och * 8 + o;
                    p[((size_t)(img0 + img) * 16 + oc) * 25 + py * 5 + (x >> 1)] = v;
                }
            }
        }
    }
}

__global__ void __launch_bounds__(256, 2) fused_kernel(
    const float* __restrict__ node_fea, const float* __restrict__ edge_fea,
    const int* __restrict__ eidx,
    const float* g1w, const float* g1as, const float* g1ad,
    const float* g1we, const float* g1ae, const float* g1b,
    const float* g2w, const float* g2as, const float* g2ad,
    const float* g2we, const float* g2ae, const float* g2b,
    const float* __restrict__ fc1w, const float* __restrict__ fc1b,
    float* __restrict__ gcontrib,
    const float* __restrict__ pic,
    const float* __restrict__ c1w, const float* __restrict__ c1b,
    const float* __restrict__ c2w, const float* __restrict__ c2b,
    float* __restrict__ p) {
    __shared__ SMem u;
    if (blockIdx.x == 0) {
        gnn_run(u.g, node_fea, edge_fea, eidx,
                g1w, g1as, g1ad, g1we, g1ae, g1b,
                g2w, g2as, g2ad, g2we, g2ae, g2b,
                fc1w, fc1b, gcontrib);
    } else {
        conv_path(u.c, (blockIdx.x - 1) * 2, pic, c1w, c1b, c2w, c2b, p);
    }
}

// ---------------------------------------------------------------------------
// FC1: h[b,j] = relu(gcontrib[j] + sum_k p[b,k]*w2[k,j]); w2 = fc1_w[960:,:]
// ---------------------------------------------------------------------------
#define FC1_ROWS 16
__global__ void fc1_kernel(
    const float* __restrict__ p, const float* __restrict__ w,
    const float* __restrict__ gcontrib, float* __restrict__ h) {
    __shared__ float sp[FC1_ROWS * 400];
    const int tid = threadIdx.x;
    const size_t r0 = (size_t)blockIdx.x * FC1_ROWS;
    for (int i = tid; i < FC1_ROWS * 400; i += 256) sp[i] = p[r0 * 400 + i];
    __syncthreads();
    const int c0 = tid, c1 = tid + 256;
    float acc[FC1_ROWS][2];
#pragma unroll
    for (int r = 0; r < FC1_ROWS; ++r) { acc[r][0] = 0.f; acc[r][1] = 0.f; }
    for (int k = 0; k < 400; k += 4) {
        float wa0 = w[(size_t)(k + 0) * 512 + c0], wa1 = w[(size_t)(k + 0) * 512 + c1];
        float wb0 = w[(size_t)(k + 1) * 512 + c0], wb1 = w[(size_t)(k + 1) * 512 + c1];
        float wc0 = w[(size_t)(k + 2) * 512 + c0], wc1 = w[(size_t)(k + 2) * 512 + c1];
        float wd0 = w[(size_t)(k + 3) * 512 + c0], wd1 = w[(size_t)(k + 3) * 512 + c1];
#pragma unroll
        for (int r = 0; r < FC1_ROWS; ++r) {
            float4 pv = *(const float4*)&sp[r * 400 + k];
            acc[r][0] += pv.x * wa0 + pv.y * wb0 + pv.z * wc0 + pv.w * wd0;
            acc[r][1] += pv.x * wa1 + pv.y * wb1 + pv.z * wc1 + pv.w * wd1;
        }
    }
    float g0 = gcontrib[c0], g1 = gcontrib[c1];
#pragma unroll
    for (int r = 0; r < FC1_ROWS; ++r) {
        h[(r0 + r) * 512 + c0] = fmaxf(acc[r][0] + g0, 0.f);
        h[(r0 + r) * 512 + c1] = fmaxf(acc[r][1] + g1, 0.f);
    }
}

// ---------------------------------------------------------------------------
// FC2: out[b,j] = tanh(sum_k h[b,k]*fc2_w[k,j] + fc2_b[j]); one wave per row
// ---------------------------------------------------------------------------
__global__ void fc2_kernel(
    const float* __restrict__ h, const float* __restrict__ w,
    const float* __restrict__ b, float* __restrict__ out) {
    const int wave = threadIdx.x >> 6, lane = threadIdx.x & 63;
    const size_t row = (size_t)blockIdx.x * 4 + wave;
    const float* hr = h + row * 512;
    float partial[10];
#pragma unroll
    for (int j = 0; j < 10; ++j) partial[j] = 0.f;
    for (int k = lane; k < 512; k += 64) {
        float hv = hr[k];
        const float* wr = w + (size_t)k * 10;
#pragma unroll
        for (int j = 0; j < 10; ++j) partial[j] += hv * wr[j];
    }
#pragma unroll
    for (int j = 0; j < 10; ++j) {
        float v = partial[j];
        for (int sft = 32; sft > 0; sft >>= 1) v += __shfl_xor(v, sft, 64);
        partial[j] = v;
    }
    if (lane == 0) {
#pragma unroll
        for (int j = 0; j < 10; ++j)
            out[row * 10 + j] = tanhf(partial[j] + b[j]);
    }
}

extern "C" void kernel_launch(void* const* d_in, const int* in_sizes, int n_in,
                              void* d_out, int out_size, void* d_ws, size_t ws_size,
                              hipStream_t stream) {
    const float* node_fea = (const float*)d_in[0];
    const float* edge_fea = (const float*)d_in[1];
    const float* pic      = (const float*)d_in[2];
    const float* c1w = (const float*)d_in[3];
    const float* c1b = (const float*)d_in[4];
    const float* c2w = (const float*)d_in[5];
    const float* c2b = (const float*)d_in[6];
    const float* g1w  = (const float*)d_in[7];
    const float* g1as = (const float*)d_in[8];
    const float* g1ad = (const float*)d_in[9];
    const float* g1we = (const float*)d_in[10];
    const float* g1ae = (const float*)d_in[11];
    const float* g1b  = (const float*)d_in[12];
    const float* g2w  = (const float*)d_in[13];
    const float* g2as = (const float*)d_in[14];
    const float* g2ad = (const float*)d_in[15];
    const float* g2we = (const float*)d_in[16];
    const float* g2ae = (const float*)d_in[17];
    const float* g2b  = (const float*)d_in[18];
    const float* fc1w = (const float*)d_in[19];
    const float* fc1b = (const float*)d_in[20];
    const float* fc2w = (const float*)d_in[21];
    const float* fc2b = (const float*)d_in[22];
    const int*   eidx = (const int*)d_in[23];
    float* out = (float*)d_out;

    char* ws = (char*)d_ws;
    float* gcontrib = (float*)ws;                                   // 512 f
    float* p = (float*)(ws + 2048);                                 // 8192*400 f
    float* h = (float*)(ws + 2048 + (size_t)8192 * 400 * 4);        // 8192*512 f

    hipLaunchKernelGGL(fused_kernel, dim3(4097), dim3(256), 0, stream,
                       node_fea, edge_fea, eidx,
                       g1w, g1as, g1ad, g1we, g1ae, g1b,
                       g2w, g2as, g2ad, g2we, g2ae, g2b,
                       fc1w, fc1b, gcontrib,
                       pic, c1w, c1b, c2w, c2b, p);
    hipLaunchKernelGGL(fc1_kernel, dim3(8192 / FC1_ROWS), dim3(256), 0, stream,
                       p, fc1w + (size_t)960 * 512, gcontrib, h);
    hipLaunchKernelGGL(fc2_kernel, dim3(8192 / 4), dim3(256), 0, stream,
                       h, fc2w, fc2b, out);
}